// Round 4
// baseline (388.044 us; speedup 1.0000x reference)
//
#include <hip/hip_runtime.h>

// VQ-VAE VectorQuantizer: B=32, C=D=64, H=W=64, K=512
// d_in[0]: inputs  [32,64,64,64] f32 (NCHW, C = embedding dim)
// d_in[1]: embedding [512,64] f32
// d_out: [loss(1) | out(32*64*64*64) | indices(32*4096)] all read as f32
//
// V5: latency/TLP fix of V4's MFMA screen + exact rescore.
// V4 measured 233us with MfmaUtil 8.7 / VALUBusy 7.9 / Occ 6.9%: pipes idle,
// pure unhidden latency at 2 waves/SIMD with barrier-phased 4-wave blocks.
// Changes: (1) 1-wave blocks, pt=2 -> 32 pos/wave, grid=4096 = 16 waves/CU,
// no barriers; (2) register double-buffered bfrag loads; (3) MFMA chain split
// into 3 independent 2-chains (aH,aM,aL) combined by two ordered fp32 adds
// (same formula in BOTH sweeps -> bit-identical screen, emit logic unchanged);
// (4) 2 launches total: fused prep (e2+bfrag+zero), last-block-ticket finalize.
//
// Exactness (unchanged from V4, which passed): numpy argmin_k
// fl(fl(x2-2xe_k)+e2_k) preserved by screening s~_k = e2_k + sum((-2x)*e) in
// bf16 hi/lo split MFMA (|err| <= ~5e-5 incl numpy's own rounding window),
// emitting all k with s~_k <= min+EPS (EPS=1e-3, >10x margin; CAP=6 overflow
// -> exact full scan), exact fmaf rescore with lexicographic (u,k) min.

#define KCODE  512
#define EMB    64
#define HWSZ   4096
#define NPOS   131072
#define BLKPOS 32
#define GRID   (NPOS / BLKPOS)   // 4096 one-wave blocks
#define EPSW   1e-3f
#define CAP    6

typedef short short8  __attribute__((ext_vector_type(8)));
typedef float float4v __attribute__((ext_vector_type(4)));

// ws float layout:
//   [0]          loss accumulator (device atomicAdd)
//   [1]          ticket counter (as unsigned)
//   [512..1023]  e2 (numpy rounding, by code)
//   [1024..]     B-fragments: short8[32][2][2][64]  (128 KB)

// ---------- numpy-exact helpers ----------
__device__ __forceinline__ float np_sumsq64(const float* a) {
    #pragma clang fp contract(off)
    {
        float r0 = a[0] * a[0], r1 = a[1] * a[1], r2 = a[2] * a[2], r3 = a[3] * a[3];
        float r4 = a[4] * a[4], r5 = a[5] * a[5], r6 = a[6] * a[6], r7 = a[7] * a[7];
        for (int i = 8; i < 64; i += 8) {
            r0 += a[i + 0] * a[i + 0];
            r1 += a[i + 1] * a[i + 1];
            r2 += a[i + 2] * a[i + 2];
            r3 += a[i + 3] * a[i + 3];
            r4 += a[i + 4] * a[i + 4];
            r5 += a[i + 5] * a[i + 5];
            r6 += a[i + 6] * a[i + 6];
            r7 += a[i + 7] * a[i + 7];
        }
        return ((r0 + r1) + (r2 + r3)) + ((r4 + r5) + (r6 + r7));
    }
}

// exact numpy distance core: u = fl(fl(x2 - 2*xe) + e2k)  (proven round 0)
__device__ __forceinline__ float exact_u(const float* x, float x2,
                                         const float* ek, float e2k) {
    float t0 = 0.f, t1 = 0.f, t2 = 0.f, t3 = 0.f;
    #pragma unroll
    for (int c = 0; c < EMB; c += 4) {
        t0 = fmaf(x[c + 0], ek[c + 0], t0);
        t1 = fmaf(x[c + 1], ek[c + 1], t1);
        t2 = fmaf(x[c + 2], ek[c + 2], t2);
        t3 = fmaf(x[c + 3], ek[c + 3], t3);
    }
    float xe  = (t0 + t1) + (t2 + t3);
    float tmp = x2 - 2.0f * xe;     // 2*xe exact -> contraction rounding-identical
    return tmp + e2k;
}

__device__ __forceinline__ unsigned short bf16rne(float f) {
    unsigned u = __float_as_uint(f);
    unsigned r = (u + 0x7FFFu + ((u >> 16) & 1u)) >> 16;   // round-nearest-even
    return (unsigned short)r;
}
__device__ __forceinline__ float bf16tof(unsigned short h) {
    return __uint_as_float((unsigned)h << 16);
}

// Screen tile: s~ for 16 positions x 16 codes. 3 independent 2-deep MFMA
// chains (dependent-latency -> issue-bound), combined by ordered fp32 adds.
// Called identically in sweep 1 and sweep 2 -> bit-identical values.
__device__ __forceinline__ float4v screen_tile(
        const short8 fh0, const short8 fh1, const short8 fl0, const short8 fl1,
        const short8 eh0, const short8 eh1, const short8 el0, const short8 el1,
        const float e2v) {
    float4v aH = {e2v, e2v, e2v, e2v};
    float4v aM = {0.f, 0.f, 0.f, 0.f};
    float4v aL = {0.f, 0.f, 0.f, 0.f};
    aH = __builtin_amdgcn_mfma_f32_16x16x32_bf16(fh0, eh0, aH, 0, 0, 0);
    aM = __builtin_amdgcn_mfma_f32_16x16x32_bf16(fh0, el0, aM, 0, 0, 0);
    aL = __builtin_amdgcn_mfma_f32_16x16x32_bf16(fl0, eh0, aL, 0, 0, 0);
    aH = __builtin_amdgcn_mfma_f32_16x16x32_bf16(fh1, eh1, aH, 0, 0, 0);
    aM = __builtin_amdgcn_mfma_f32_16x16x32_bf16(fh1, el1, aM, 0, 0, 0);
    aL = __builtin_amdgcn_mfma_f32_16x16x32_bf16(fl1, eh1, aL, 0, 0, 0);
    float4v s;
    #pragma unroll
    for (int r = 0; r < 4; ++r) s[r] = (aH[r] + aM[r]) + aL[r];
    return s;
}

// ---------- fused prep: e2 + bfrag + counter zeroing ----------
__global__ void vq_prep(const float* __restrict__ emb, float* __restrict__ ws) {
    int f = blockIdx.x * blockDim.x + threadIdx.x;   // 0..4095
    if (f == 0) { ws[0] = 0.0f; ((unsigned*)ws)[1] = 0u; }
    if (f < KCODE) ws[512 + f] = np_sumsq64(emb + f * EMB);
    // bfrag: frag index f = t*256 + c*128 + hl*64 + lane; element j holds
    // e[code = 16t + (lane&15)][d = 32c + (lane>>4)*8 + j] split hi/lo bf16.
    short8* bfrag = (short8*)(ws + 1024);
    int l = f & 63;
    int c = (f >> 6) & 1;
    int t = f >> 7;            // 0..31
    int code  = t * 16 + (l & 15);
    int dbase = 32 * c + ((l >> 4) & 3) * 8;
    const float* e = emb + code * EMB + dbase;
    short8 h, lo;
    #pragma unroll
    for (int j = 0; j < 8; ++j) {
        float v = e[j];
        unsigned short hb = bf16rne(v);
        float hf = bf16tof(hb);
        unsigned short lb = bf16rne(v - hf);
        h[j]  = (short)hb;
        lo[j] = (short)lb;
    }
    bfrag[t * 256 + c * 128 + 0 * 64 + l] = h;
    bfrag[t * 256 + c * 128 + 1 * 64 + l] = lo;
}

// ---------- main kernel: one wave per 32 positions ----------
__global__ __launch_bounds__(64, 4) void vq_main(
        const float*  __restrict__ in,        // [32,64,4096]
        const float*  __restrict__ emb,       // [512,64]
        float*        __restrict__ ws,        // workspace base
        float*        __restrict__ out_loss,  // d_out+0
        float*        __restrict__ out_q,     // d_out+1
        float*        __restrict__ out_idx) { // d_out+1+NPOS*EMB
    const float*  e2np     = ws + 512;
    const short8* bfrag    = (const short8*)(ws + 1024);
    float*        loss_acc = ws;
    unsigned*     ticket   = (unsigned*)ws + 1;

    __shared__ int            cnt[BLKPOS];
    __shared__ unsigned short ks[BLKPOS][CAP];

    const int lane = threadIdx.x;       // 0..63 (one wave)
    const int lg   = lane >> 4;         // dim-group (A) / row-group (C)
    const int lc   = lane & 15;         // position (A-row) / code (C-col)
    const int blockPos = blockIdx.x * BLKPOS;

    if (lane < BLKPOS) cnt[lane] = 0;
    __syncthreads();

    // ---- pack A-fragments: 2 position-tiles x 2 dim-chunks, hi/lo of (-2x)
    // A element j of lane: row = lane&15 (position), k = (lane>>4)*8+j (dim).
    short8 fH[2][2], fL[2][2];
    #pragma unroll
    for (int pt = 0; pt < 2; ++pt) {
        int pos = blockPos + pt * 16 + lc;
        int b   = pos >> 12;
        int hw  = pos & (HWSZ - 1);
        const float* xb = in + ((size_t)b << 18) + hw;
        #pragma unroll
        for (int c = 0; c < 2; ++c) {
            short8 h, lo;
            #pragma unroll
            for (int j = 0; j < 8; ++j) {
                int d = 32 * c + lg * 8 + j;
                float g = -2.0f * xb[(size_t)d << 12];   // exact scale
                unsigned short hb = bf16rne(g);
                float hf = bf16tof(hb);
                unsigned short lb = bf16rne(g - hf);
                h[j]  = (short)hb;
                lo[j] = (short)lb;
            }
            fH[pt][c] = h;
            fL[pt][c] = lo;
        }
    }

    // ---- sweep 1: per-position running min of s~ (prefetched bfrag) ----
    float m0[4], m1[4];
    #pragma unroll
    for (int r = 0; r < 4; ++r) { m0[r] = 3.4e38f; m1[r] = 3.4e38f; }

    short8 peh0 = bfrag[lane], pel0 = bfrag[64 + lane];
    short8 peh1 = bfrag[128 + lane], pel1 = bfrag[192 + lane];
    float  pe2  = e2np[lc];
    for (int t = 0; t < 32; ++t) {
        const short8 eh0 = peh0, el0 = pel0, eh1 = peh1, el1 = pel1;
        const float  e2v = pe2;
        if (t < 31) {
            const short8* nb = bfrag + (t + 1) * 256;
            peh0 = nb[lane];       pel0 = nb[64 + lane];
            peh1 = nb[128 + lane]; pel1 = nb[192 + lane];
            pe2  = e2np[(t + 1) * 16 + lc];
        }
        float4v s0 = screen_tile(fH[0][0], fH[0][1], fL[0][0], fL[0][1],
                                 eh0, eh1, el0, el1, e2v);
        float4v s1 = screen_tile(fH[1][0], fH[1][1], fL[1][0], fL[1][1],
                                 eh0, eh1, el0, el1, e2v);
        #pragma unroll
        for (int r = 0; r < 4; ++r) {
            m0[r] = fminf(m0[r], s0[r]);
            m1[r] = fminf(m1[r], s1[r]);
        }
    }

    // cross-lane min over the 16-lane code group (masks <16 stay in-group);
    // per (pt,r) the position is pt*16 + lg*4 + r.
    #pragma unroll
    for (int r = 0; r < 4; ++r) {
        float v = m0[r];
        v = fminf(v, __shfl_xor(v, 1, 64));
        v = fminf(v, __shfl_xor(v, 2, 64));
        v = fminf(v, __shfl_xor(v, 4, 64));
        v = fminf(v, __shfl_xor(v, 8, 64));
        m0[r] = v + EPSW;
        float w = m1[r];
        w = fminf(w, __shfl_xor(w, 1, 64));
        w = fminf(w, __shfl_xor(w, 2, 64));
        w = fminf(w, __shfl_xor(w, 4, 64));
        w = fminf(w, __shfl_xor(w, 8, 64));
        m1[r] = w + EPSW;
    }

    // ---- sweep 2: bit-identical recompute, emit candidates ----
    peh0 = bfrag[lane]; pel0 = bfrag[64 + lane];
    peh1 = bfrag[128 + lane]; pel1 = bfrag[192 + lane];
    pe2  = e2np[lc];
    for (int t = 0; t < 32; ++t) {
        const short8 eh0 = peh0, el0 = pel0, eh1 = peh1, el1 = pel1;
        const float  e2v = pe2;
        if (t < 31) {
            const short8* nb = bfrag + (t + 1) * 256;
            peh0 = nb[lane];       pel0 = nb[64 + lane];
            peh1 = nb[128 + lane]; pel1 = nb[192 + lane];
            pe2  = e2np[(t + 1) * 16 + lc];
        }
        float4v s0 = screen_tile(fH[0][0], fH[0][1], fL[0][0], fL[0][1],
                                 eh0, eh1, el0, el1, e2v);
        float4v s1 = screen_tile(fH[1][0], fH[1][1], fL[1][0], fL[1][1],
                                 eh0, eh1, el0, el1, e2v);
        #pragma unroll
        for (int r = 0; r < 4; ++r) {
            if (s0[r] <= m0[r]) {
                int p = 0 * 16 + lg * 4 + r;
                int slot = atomicAdd(&cnt[p], 1);
                if (slot < CAP) ks[p][slot] = (unsigned short)(t * 16 + lc);
            }
            if (s1[r] <= m1[r]) {
                int p = 1 * 16 + lg * 4 + r;
                int slot = atomicAdd(&cnt[p], 1);
                if (slot < CAP) ks[p][slot] = (unsigned short)(t * 16 + lc);
            }
        }
    }
    __syncthreads();   // candidate lists complete (single wave: waitcnt only)

    // ---- exact rescore: lanes 0..31, one position each ----
    int bk = 0;
    if (lane < BLKPOS) {
        const int n  = blockPos + lane;
        const int b  = n >> 12;
        const int hw = n & (HWSZ - 1);
        const float* xp = in + ((size_t)b << 18) + hw;
        float x[EMB];
        #pragma unroll
        for (int c = 0; c < EMB; ++c) x[c] = xp[(size_t)c << 12];
        const float x2 = np_sumsq64(x);

        int count = cnt[lane];
        float bu = 3.4e38f;
        if (count >= 1 && count <= CAP) {
            bk = 0x7fffffff;
            for (int i = 0; i < count; ++i) {
                int k  = ks[lane][i];
                float u = exact_u(x, x2, emb + k * EMB, e2np[k]);
                if (u < bu || (u == bu && k < bk)) { bu = u; bk = k; }
            }
        } else {
            // overflow safety net: exact full scan, first-min semantics
            for (int k = 0; k < KCODE; ++k) {
                float u = exact_u(x, x2, emb + k * EMB, e2np[k]);
                if (u < bu) { bu = u; bk = k; }
            }
        }
        out_idx[n] = (float)bk;
    }

    // broadcast each position's winner to both dim-half lanes
    const int p   = lane & 31;
    const int hfl = lane >> 5;          // dim half: 0 -> d<32, 1 -> d>=32
    const int bkp = __shfl(bk, p, 64);

    // ---- write quantized output + loss partial (32 dims per lane) ----
    const int n  = blockPos + p;
    const int b  = n >> 12;
    const int hw = n & (HWSZ - 1);
    const size_t doff = ((size_t)(hfl * 32) << 12);
    const float*  xh = in    + ((size_t)b << 18) + doff + hw;
    float*        op = out_q + ((size_t)b << 18) + doff + hw;
    const float4* q4 = (const float4*)(emb + (size_t)bkp * EMB + hfl * 32);
    float s = 0.0f;
    #pragma unroll
    for (int c4 = 0; c4 < 8; ++c4) {
        float4 v = q4[c4];
        float a0 = xh[(size_t)(c4 * 4 + 0) << 12];
        float a1 = xh[(size_t)(c4 * 4 + 1) << 12];
        float a2 = xh[(size_t)(c4 * 4 + 2) << 12];
        float a3 = xh[(size_t)(c4 * 4 + 3) << 12];
        float d0 = v.x - a0, d1 = v.y - a1, d2 = v.z - a2, d3 = v.w - a3;
        s = fmaf(d0, d0, s); s = fmaf(d1, d1, s);
        s = fmaf(d2, d2, s); s = fmaf(d3, d3, s);
        op[(size_t)(c4 * 4 + 0) << 12] = v.x;
        op[(size_t)(c4 * 4 + 1) << 12] = v.y;
        op[(size_t)(c4 * 4 + 2) << 12] = v.z;
        op[(size_t)(c4 * 4 + 3) << 12] = v.w;
    }

    // wave-reduce loss partial; last block finalizes (no extra launch)
    #pragma unroll
    for (int off = 32; off > 0; off >>= 1)
        s += __shfl_down(s, off, 64);
    if (lane == 0) {
        atomicAdd(loss_acc, s);
        __threadfence();
        unsigned tk = atomicAdd(ticket, 1u);
        if (tk == (unsigned)(GRID - 1)) {
            float v = atomicAdd(loss_acc, 0.0f);   // coherent read of final sum
            out_loss[0] = 1.25f * v * (1.0f / ((float)NPOS * (float)EMB));
        }
    }
}

extern "C" void kernel_launch(void* const* d_in, const int* in_sizes, int n_in,
                              void* d_out, int out_size, void* d_ws, size_t ws_size,
                              hipStream_t stream) {
    const float* in  = (const float*)d_in[0];
    const float* emb = (const float*)d_in[1];
    float* ws  = (float*)d_ws;
    float* out = (float*)d_out;

    float* out_loss = out;
    float* out_q    = out + 1;
    float* out_idx  = out + 1 + (size_t)NPOS * EMB;

    vq_prep<<<16, 256, 0, stream>>>(emb, ws);
    vq_main<<<GRID, 64, 0, stream>>>(in, emb, ws, out_loss, out_q, out_idx);
}

// Round 5
// 203.386 us; speedup vs baseline: 1.9079x; 1.9079x over previous
//
#include <hip/hip_runtime.h>

// VQ-VAE VectorQuantizer: B=32, C=D=64, H=W=64, K=512
// d_in[0]: inputs  [32,64,64,64] f32 (NCHW, C = embedding dim)
// d_in[1]: embedding [512,64] f32
// d_out: [loss(1) | out(32*64*64*64) | indices(32*4096)] all read as f32
//
// V6: single-sweep MFMA screen with in-register top-3 (m1,i1)(m2,i2)(m3),
// resolution moved out of the hot kernel.
// V5 post-mortem: launch_bounds(64,4) -> VGPR=64 -> x[64] rescore +
// double-buffered fragments spilled to scratch; per-wave lifetime 139us.
// Fix: one register regime per kernel.
//   vq_screen: MFMA sweep only (no x[64], no LDS lists). Tracks top-3
//     per position. If m2-m1 > DELTA the screen argmin is provably numpy's
//     argmin; else pack {i1,i2,g2,g3} (exact in fp32, <2^20) into out_idx.
//     g3 (m3 also within DELTA, ~0.2%) additionally listed in ws.
//   vq_full: wave-per-position exact 512-scan for listed g3 positions.
//   vq_write: bandwidth kernel; owns x[64] (needed for loss anyway);
//     resolves g2 pairs with exact_u in-register (~600cyc, ~4.5% of lanes);
//     inline full-scan only for unlisted g3 overflow (statistically never).
// Decision bound: |(s~_k - s~_j) - (u_k - u_j)| <= ~1e-4 hard
//   (bf16 hi/lo split residuals <=1.6e-5 w/ max|x|<=5.5, MFMA fp32 accum
//    <=2.4e-5, numpy fl() windows <=8e-6, x2 cancels in differences).
//   DELTA = 2.5e-4 (2.5x margin).

#define KCODE 512
#define EMB   64
#define HWSZ  4096
#define NPOS  131072
#define DELTA 2.5e-4f

typedef short short8  __attribute__((ext_vector_type(8)));
typedef float float4v __attribute__((ext_vector_type(4)));

// ws float layout:
//   [0]        fullCnt (uint)     [1] writer ticket (uint)   [2..7] pad
//   [8..519]   writer block partials (512)
//   [520..1031] e2 (numpy rounding, by code)
//   [1032..33799] bfrag short8[32][2][2][64] (128 KB)
//   [33800..]  g3 full-scan list (cap from ws_size, <=1024)

// ---------- numpy-exact helpers ----------
__device__ __forceinline__ float np_sumsq64(const float* a) {
    #pragma clang fp contract(off)
    {
        float r0 = a[0] * a[0], r1 = a[1] * a[1], r2 = a[2] * a[2], r3 = a[3] * a[3];
        float r4 = a[4] * a[4], r5 = a[5] * a[5], r6 = a[6] * a[6], r7 = a[7] * a[7];
        for (int i = 8; i < 64; i += 8) {
            r0 += a[i + 0] * a[i + 0];
            r1 += a[i + 1] * a[i + 1];
            r2 += a[i + 2] * a[i + 2];
            r3 += a[i + 3] * a[i + 3];
            r4 += a[i + 4] * a[i + 4];
            r5 += a[i + 5] * a[i + 5];
            r6 += a[i + 6] * a[i + 6];
            r7 += a[i + 7] * a[i + 7];
        }
        return ((r0 + r1) + (r2 + r3)) + ((r4 + r5) + (r6 + r7));
    }
}

// exact numpy distance: u = fl(fl(x2 - 2*xe) + e2k)  (round-0-proven)
__device__ __forceinline__ float exact_u(const float* x, float x2,
                                         const float* ek, float e2k) {
    float t0 = 0.f, t1 = 0.f, t2 = 0.f, t3 = 0.f;
    #pragma unroll
    for (int c = 0; c < EMB; c += 4) {
        t0 = fmaf(x[c + 0], ek[c + 0], t0);
        t1 = fmaf(x[c + 1], ek[c + 1], t1);
        t2 = fmaf(x[c + 2], ek[c + 2], t2);
        t3 = fmaf(x[c + 3], ek[c + 3], t3);
    }
    float xe  = (t0 + t1) + (t2 + t3);
    float tmp = x2 - 2.0f * xe;     // 2*xe exact -> contraction rounding-identical
    return tmp + e2k;
}

__device__ __forceinline__ unsigned short bf16rne(float f) {
    unsigned u = __float_as_uint(f);
    unsigned r = (u + 0x7FFFu + ((u >> 16) & 1u)) >> 16;
    return (unsigned short)r;
}
__device__ __forceinline__ float bf16tof(unsigned short h) {
    return __uint_as_float((unsigned)h << 16);
}

// sorted-insert of (v,i) into ((M1,I1),(M2,I2),M3); strict < keeps earlier.
#define INS(M1, I1, M2, I2, M3, v, i)                      \
    {                                                      \
        bool lt1 = (v) < (M1), lt2 = (v) < (M2), lt3 = (v) < (M3); \
        (M3) = lt2 ? (M2) : (lt3 ? (v) : (M3));            \
        (I2) = lt1 ? (I1) : (lt2 ? (i) : (I2));            \
        (M2) = lt1 ? (M1) : (lt2 ? (v) : (M2));            \
        (M1) = lt1 ? (v) : (M1);                           \
        (I1) = lt1 ? (i) : (I1);                           \
    }

// ---------- prep: e2 + bfrag + counter zeroing ----------
__global__ void vq_prep(const float* __restrict__ emb, float* __restrict__ ws) {
    int f = blockIdx.x * blockDim.x + threadIdx.x;   // 0..4095
    if (f == 0) { ((unsigned*)ws)[0] = 0u; ((unsigned*)ws)[1] = 0u; }
    if (f < KCODE) ws[520 + f] = np_sumsq64(emb + f * EMB);
    short8* bfrag = (short8*)(ws + 1032);
    int l = f & 63;
    int c = (f >> 6) & 1;
    int t = f >> 7;            // 0..31
    int code  = t * 16 + (l & 15);
    int dbase = 32 * c + ((l >> 4) & 3) * 8;
    const float* e = emb + code * EMB + dbase;
    short8 h, lo;
    #pragma unroll
    for (int j = 0; j < 8; ++j) {
        float v = e[j];
        unsigned short hb = bf16rne(v);
        float hf = bf16tof(hb);
        unsigned short lb = bf16rne(v - hf);
        h[j]  = (short)hb;
        lo[j] = (short)lb;
    }
    bfrag[t * 256 + c * 128 + 0 * 64 + l] = h;
    bfrag[t * 256 + c * 128 + 1 * 64 + l] = lo;
}

// ---------- screen: single MFMA sweep, top-3 tracking ----------
__global__ __launch_bounds__(256, 3) void vq_screen(
        const float*  __restrict__ in,
        const float*  __restrict__ e2np,      // ws+520
        const short8* __restrict__ bfrag,     // ws+1032
        float*        __restrict__ out_idx,   // packed {i1,i2,g2,g3}
        unsigned*     __restrict__ fullCnt,   // ws+0
        unsigned*     __restrict__ fullList,  // ws+33800
        int fullCap) {
    const int tid  = threadIdx.x;
    const int wave = tid >> 6;
    const int lane = tid & 63;
    const int lg   = lane >> 4;
    const int lc   = lane & 15;
    const int wavePos = blockIdx.x * 128 + wave * 32;

    // A-fragments: 2 pos-tiles x 2 dim-chunks, hi/lo of g = -2x.
    // A element j of lane: row = lane&15 (position), k-dim = (lane>>4)*8+j.
    short8 fH[2][2], fL[2][2];
    #pragma unroll
    for (int pt = 0; pt < 2; ++pt) {
        int pos = wavePos + pt * 16 + lc;
        int b   = pos >> 12;
        int hw  = pos & (HWSZ - 1);
        const float* xb = in + ((size_t)b << 18) + hw;
        #pragma unroll
        for (int c = 0; c < 2; ++c) {
            short8 h, lo;
            #pragma unroll
            for (int j = 0; j < 8; ++j) {
                int d = 32 * c + lg * 8 + j;
                float g = -2.0f * xb[(size_t)d << 12];
                unsigned short hb = bf16rne(g);
                float hf = bf16tof(hb);
                unsigned short lb = bf16rne(g - hf);
                h[j]  = (short)hb;
                lo[j] = (short)lb;
            }
            fH[pt][c] = h;
            fL[pt][c] = lo;
        }
    }

    float m1[2][4], m2[2][4], m3[2][4];
    int   i1[2][4], i2[2][4];
    #pragma unroll
    for (int pt = 0; pt < 2; ++pt)
        #pragma unroll
        for (int r = 0; r < 4; ++r) {
            m1[pt][r] = 3.4e38f; m2[pt][r] = 3.4e38f; m3[pt][r] = 3.4e38f;
            i1[pt][r] = 0;       i2[pt][r] = 0;
        }

    // t-loop with register prefetch of next B tile (4x b128 + e2)
    short8 ceh0 = bfrag[lane],       cel0 = bfrag[64 + lane];
    short8 ceh1 = bfrag[128 + lane], cel1 = bfrag[192 + lane];
    float  ce2  = e2np[lc];
    #pragma unroll 2
    for (int t = 0; t < 32; ++t) {
        short8 neh0, nel0, neh1, nel1;
        float  ne2 = 0.0f;
        if (t < 31) {
            const short8* nb = bfrag + (t + 1) * 256;
            neh0 = nb[lane];       nel0 = nb[64 + lane];
            neh1 = nb[128 + lane]; nel1 = nb[192 + lane];
            ne2  = e2np[(t + 1) * 16 + lc];
        }
        const int kf = t * 16 + lc;
        #pragma unroll
        for (int pt = 0; pt < 2; ++pt) {
            float4v aH = {ce2, ce2, ce2, ce2};
            float4v aM = {0.f, 0.f, 0.f, 0.f};
            float4v aL = {0.f, 0.f, 0.f, 0.f};
            aH = __builtin_amdgcn_mfma_f32_16x16x32_bf16(fH[pt][0], ceh0, aH, 0, 0, 0);
            aM = __builtin_amdgcn_mfma_f32_16x16x32_bf16(fH[pt][0], cel0, aM, 0, 0, 0);
            aL = __builtin_amdgcn_mfma_f32_16x16x32_bf16(fL[pt][0], ceh0, aL, 0, 0, 0);
            aH = __builtin_amdgcn_mfma_f32_16x16x32_bf16(fH[pt][1], ceh1, aH, 0, 0, 0);
            aM = __builtin_amdgcn_mfma_f32_16x16x32_bf16(fH[pt][1], cel1, aM, 0, 0, 0);
            aL = __builtin_amdgcn_mfma_f32_16x16x32_bf16(fL[pt][1], ceh1, aL, 0, 0, 0);
            #pragma unroll
            for (int r = 0; r < 4; ++r) {
                float sv = (aH[r] + aM[r]) + aL[r];
                INS(m1[pt][r], i1[pt][r], m2[pt][r], i2[pt][r], m3[pt][r], sv, kf);
            }
        }
        ceh0 = neh0; cel0 = nel0; ceh1 = neh1; cel1 = nel1; ce2 = ne2;
    }

    // cross-lane top-3 merge over the 16-lane code group
    #pragma unroll
    for (int pt = 0; pt < 2; ++pt) {
        #pragma unroll
        for (int r = 0; r < 4; ++r) {
            float M1 = m1[pt][r], M2 = m2[pt][r], M3 = m3[pt][r];
            int   I1 = i1[pt][r], I2 = i2[pt][r];
            #pragma unroll
            for (int d = 1; d <= 8; d <<= 1) {
                float pm1 = __shfl_xor(M1, d, 64);
                int   pi1 = __shfl_xor(I1, d, 64);
                float pm2 = __shfl_xor(M2, d, 64);
                int   pi2 = __shfl_xor(I2, d, 64);
                float pm3 = __shfl_xor(M3, d, 64);
                INS(M1, I1, M2, I2, M3, pm1, pi1);
                INS(M1, I1, M2, I2, M3, pm2, pi2);
                M3 = fminf(M3, pm3);    // pm3 >= pm2 >= post-insert M2
            }
            m1[pt][r] = M1; m2[pt][r] = M2; m3[pt][r] = M3;
            i1[pt][r] = I1; i2[pt][r] = I2;
        }
    }

    if (lc == 0) {
        #pragma unroll
        for (int pt = 0; pt < 2; ++pt) {
            #pragma unroll
            for (int r = 0; r < 4; ++r) {
                int p  = wavePos + pt * 16 + lg * 4 + r;
                int g2 = (m2[pt][r] - m1[pt][r] <= DELTA) ? 1 : 0;
                int g3 = (m3[pt][r] - m1[pt][r] <= DELTA) ? 1 : 0;
                int packed = i1[pt][r] | (i2[pt][r] << 9) | (g2 << 18) | (g3 << 19);
                out_idx[p] = (float)packed;
                if (g3) {
                    unsigned slot = atomicAdd(fullCnt, 1u);
                    if (slot < (unsigned)fullCap) fullList[slot] = (unsigned)p;
                }
            }
        }
    }
}

// ---------- exact full-scan for listed g3 positions (wave per entry) ----------
__global__ __launch_bounds__(64) void vq_full(
        const float* __restrict__ in, const float* __restrict__ emb,
        const float* __restrict__ e2np, const unsigned* __restrict__ fullCnt,
        const unsigned* __restrict__ fullList, int fullCap,
        float* __restrict__ out_idx) {
    __shared__ float xs[64];
    const int lane = threadIdx.x;
    unsigned cnt = *fullCnt;
    if (cnt > (unsigned)fullCap) cnt = (unsigned)fullCap;
    for (unsigned idx = blockIdx.x; idx < cnt; idx += gridDim.x) {
        int n = (int)fullList[idx];
        int b = n >> 12, hw = n & (HWSZ - 1);
        __syncthreads();
        xs[lane] = in[((size_t)b << 18) + ((size_t)lane << 12) + hw];
        __syncthreads();
        float x2 = np_sumsq64(xs);
        float bu = 3.4e38f;
        int   bk = 0x7fffffff;
        for (int j = 0; j < 8; ++j) {
            int k = j * 64 + lane;
            float u = exact_u(xs, x2, emb + k * EMB, e2np[k]);
            if (u < bu || (u == bu && k < bk)) { bu = u; bk = k; }
        }
        #pragma unroll
        for (int d = 1; d < 64; d <<= 1) {
            float ou = __shfl_xor(bu, d, 64);
            int   ok = __shfl_xor(bk, d, 64);
            if (ou < bu || (ou == bu && ok < bk)) { bu = ou; bk = ok; }
        }
        if (lane == 0) out_idx[n] = (float)bk;   // plain index, flags cleared
    }
}

// ---------- writer: decode/resolve, out_q, indices, loss ----------
__global__ __launch_bounds__(256) void vq_write(
        const float* __restrict__ in, const float* __restrict__ emb,
        const float* __restrict__ e2np,
        float* __restrict__ out_idx, float* __restrict__ out_q,
        float* __restrict__ partials,           // ws+8, [512]
        unsigned* __restrict__ ticket,          // ws+1
        float* __restrict__ out_loss) {
    const int tid = threadIdx.x;
    const int n   = blockIdx.x * 256 + tid;
    const int b   = n >> 12;
    const int hw  = n & (HWSZ - 1);

    const float* xp = in + ((size_t)b << 18) + hw;
    float x[EMB];
    #pragma unroll
    for (int c = 0; c < EMB; ++c) x[c] = xp[(size_t)c << 12];

    int v = (int)out_idx[n];
    int k = v & 511;
    int fl = v >> 18;
    if (fl) {
        float x2 = np_sumsq64(x);
        if (fl & 2) {
            // unlisted g3 overflow (statistically never): exact full scan
            float bu = 3.4e38f; int bk = 0;
            for (int kk = 0; kk < KCODE; ++kk) {
                float u = exact_u(x, x2, emb + kk * EMB, e2np[kk]);
                if (u < bu) { bu = u; bk = kk; }
            }
            k = bk;
        } else {
            int ia = v & 511, ib = (v >> 9) & 511;
            float u1 = exact_u(x, x2, emb + ia * EMB, e2np[ia]);
            float u2 = exact_u(x, x2, emb + ib * EMB, e2np[ib]);
            k = (u1 < u2) ? ia : (u2 < u1 ? ib : (ia < ib ? ia : ib));
        }
    }
    out_idx[n] = (float)k;

    const float4* qk = (const float4*)(emb + (size_t)k * EMB);
    float* op = out_q + ((size_t)b << 18) + hw;
    float s = 0.0f;
    #pragma unroll
    for (int c4 = 0; c4 < EMB / 4; ++c4) {
        float4 q = qk[c4];
        float d0 = q.x - x[c4 * 4 + 0];
        float d1 = q.y - x[c4 * 4 + 1];
        float d2 = q.z - x[c4 * 4 + 2];
        float d3 = q.w - x[c4 * 4 + 3];
        s = fmaf(d0, d0, s); s = fmaf(d1, d1, s);
        s = fmaf(d2, d2, s); s = fmaf(d3, d3, s);
        op[(size_t)(c4 * 4 + 0) << 12] = q.x;
        op[(size_t)(c4 * 4 + 1) << 12] = q.y;
        op[(size_t)(c4 * 4 + 2) << 12] = q.z;
        op[(size_t)(c4 * 4 + 3) << 12] = q.w;
    }

    // deterministic loss: wave shuffle -> LDS -> block partial -> ticket
    #pragma unroll
    for (int off = 32; off > 0; off >>= 1)
        s += __shfl_down(s, off, 64);
    __shared__ float red[4];
    const int wave = tid >> 6;
    const int lane = tid & 63;
    if (lane == 0) red[wave] = s;
    __syncthreads();
    if (tid == 0) {
        partials[blockIdx.x] = (red[0] + red[1]) + (red[2] + red[3]);
        __threadfence();
        unsigned tk = atomicAdd(ticket, 1u);
        if (tk == 511u) {
            __threadfence();
            float a0 = 0.f, a1 = 0.f, a2 = 0.f, a3 = 0.f;
            float a4 = 0.f, a5 = 0.f, a6 = 0.f, a7 = 0.f;
            for (int i = 0; i < 512; i += 8) {
                a0 += partials[i + 0]; a1 += partials[i + 1];
                a2 += partials[i + 2]; a3 += partials[i + 3];
                a4 += partials[i + 4]; a5 += partials[i + 5];
                a6 += partials[i + 6]; a7 += partials[i + 7];
            }
            float tot = ((a0 + a1) + (a2 + a3)) + ((a4 + a5) + (a6 + a7));
            out_loss[0] = 1.25f * tot * (1.0f / ((float)NPOS * (float)EMB));
        }
    }
}

extern "C" void kernel_launch(void* const* d_in, const int* in_sizes, int n_in,
                              void* d_out, int out_size, void* d_ws, size_t ws_size,
                              hipStream_t stream) {
    const float* in  = (const float*)d_in[0];
    const float* emb = (const float*)d_in[1];
    float* ws  = (float*)d_ws;
    float* out = (float*)d_out;

    float*    out_loss = out;
    float*    out_q    = out + 1;
    float*    out_idx  = out + 1 + (size_t)NPOS * EMB;
    unsigned* fullCnt  = (unsigned*)ws;          // ws[0]
    unsigned* ticket   = (unsigned*)ws + 1;      // ws[1]
    float*    partials = ws + 8;                 // [512]
    float*    e2np     = ws + 520;               // [512]
    short8*   bfrag    = (short8*)(ws + 1032);   // 128 KB
    unsigned* fullList = (unsigned*)(ws + 33800);

    // g3 list capacity limited by what the workspace provably holds
    long avail = (long)(ws_size / 4) - 33800;
    int  fullCap = avail > 0 ? (avail > 1024 ? 1024 : (int)avail) : 0;

    vq_prep<<<16, 256, 0, stream>>>(emb, ws);
    vq_screen<<<NPOS / 128, 256, 0, stream>>>(in, e2np, bfrag, out_idx,
                                              fullCnt, fullList, fullCap);
    vq_full<<<256, 64, 0, stream>>>(in, emb, e2np, fullCnt, fullList, fullCap,
                                    out_idx);
    vq_write<<<NPOS / 256, 256, 0, stream>>>(in, emb, e2np, out_idx, out_q,
                                             partials, ticket, out_loss);
}